// Round 4
// baseline (291.669 us; speedup 1.0000x reference)
//
#include <hip/hip_runtime.h>
#include <hip/hip_bf16.h>

typedef __bf16 bf16_t;
typedef __bf16 bf16x4 __attribute__((ext_vector_type(4)));
typedef __bf16 bf16x8 __attribute__((ext_vector_type(8)));
typedef float f32x4 __attribute__((ext_vector_type(4)));
typedef float f32x16 __attribute__((ext_vector_type(16)));

// 16B global -> LDS DMA (wave-uniform LDS base, dest = base + lane*16)
#define GLOAD_LDS16(gp, lp) __builtin_amdgcn_global_load_lds( \
    (const __attribute__((address_space(1))) void*)(gp),      \
    (__attribute__((address_space(3))) void*)(lp), 16, 0, 0)

// element index into a [rows][64] bf16 tile with XOR swizzle:
// byte ^= ((row&7)<<4)  <=>  element col ^= ((row&7)<<3)
__device__ __forceinline__ int swz64(int row, int col) {
    return row * 64 + (col ^ ((row & 7) << 3));
}

// ---------------------------------------------------------------------------
// fp32 src[R][C] -> bf16 dst[C][R]
// ---------------------------------------------------------------------------
__global__ __launch_bounds__(256) void transpose_cast_kernel(
    const float* __restrict__ src, bf16_t* __restrict__ dst, int R, int C)
{
    __shared__ float tile[32][33];
    const int bx = blockIdx.x;  // C/32
    const int by = blockIdx.y;  // R/32
    const int t  = threadIdx.x;
    const int i0 = t >> 5;      // 0..7
    const int j  = t & 31;
#pragma unroll
    for (int p = 0; p < 4; ++p) {
        int i = i0 + p * 8;
        tile[i][j] = src[(long)(by * 32 + i) * C + bx * 32 + j];
    }
    __syncthreads();
#pragma unroll
    for (int p = 0; p < 4; ++p) {
        int i = i0 + p * 8;
        dst[(long)(bx * 32 + i) * R + by * 32 + j] = (bf16_t)tile[j][i];
    }
}

// ---------------------------------------------------------------------------
// QKV + window attention v4: one block per (window PAIR, head).
// 2048 blocks x 256 thr, 48 KB LDS -> 3 blocks/CU (12 waves).
// Changes vs v3:
//  - X (A operand) read DIRECTLY from global fp32 x into registers with
//    in-reg bf16 convert (L2/XCD-resident). No X staging, no cast_x kernel.
//  - LDS holds only the W double-buffer (2 x 24 KB), overlaid by the
//    Q/K/V attention tiles; P reuses Q's tile (wave-own rows, dep-ordered).
//  - V^T scatter uses packed b64 stores (4 consecutive tokens) -> ~no
//    bank conflicts (swz64 XORs only bits >=3, preserving 4-elem runs).
// ---------------------------------------------------------------------------
__global__ __launch_bounds__(256, 3) void qkv_attn_kernel(
    const float*  __restrict__ x,     // [512 windows][64][512] fp32
    const bf16_t* __restrict__ wT,    // [1536][512]  (= w_qkv^T, bf16)
    bf16_t* __restrict__ ao)          // [32768][512] bf16, proj layout
{
    __shared__ bf16_t arena[24576];        // 48 KB
    bf16_t* const wbuf0 = arena;           // [192][64] swizzled
    bf16_t* const wbuf1 = arena + 12288;

    // XCD swizzle: a pair's 8 head-blocks on one XCD, pairs contiguous.
    const int id   = blockIdx.x;           // 0..2047
    const int xcd  = id & 7;
    const int s    = id >> 3;              // 0..255
    const int pr   = xcd * 32 + (s >> 3);  // window pair 0..255
    const int h    = s & 7;
    const int wid0 = pr * 2;

    const float* xw = x + (long)wid0 * 64 * 512;

    const int t    = threadIdx.x;
    const int wv   = t >> 6;
    const int lane = t & 63;
    const int wm   = wv >> 1;              // row half == window index
    const int wn   = wv & 1;               // col half (GEMM) / query half (attn)
    const int l31  = lane & 31;
    const int l5   = lane >> 5;
    const int rlo  = lane >> 3;            // row-within-8-block
    const int ch   = (lane & 7) ^ rlo;     // pre-swizzled source chunk

    // attention overlay (valid after post-GEMM barrier); P reuses Q's tile.
    bf16_t* const lQw = arena +    0 + wm * 12288;  // [64][64] Q, then P
    bf16_t* const lKw = arena + 4096 + wm * 12288;  // [64][64]
    bf16_t* const lVw = arena + 8192 + wm * 12288;  // V^T [d][k]
    bf16_t* const lPw = lQw;

    // stage W chunk [192][64] via global_load_lds, inverse-swizzled source
    auto stageW = [&](bf16_t* buf, int k0) {
#pragma unroll
        for (int j = 0; j < 6; ++j) {
            const int rb = wv * 6 + j;                 // 0..23
            const int nr = rb * 8 + rlo;               // 0..191
            const int grow = ((nr >> 6) << 9) + h * 64 + (nr & 63);
            GLOAD_LDS16(wT + (long)grow * 512 + k0 + ch * 8,
                        buf + rb * 512);
        }
    };

    f32x16 acc[2][3];
#pragma unroll
    for (int mi = 0; mi < 2; ++mi)
#pragma unroll
        for (int ni = 0; ni < 3; ++ni) acc[mi][ni] = (f32x16)0.0f;

    // compute one K-chunk: A from global fp32 (reg convert), B from LDS.
    auto computeW = [&](const bf16_t* lW, int k0) {
        bf16x8 aw[8];
#pragma unroll
        for (int ksi = 0; ksi < 4; ++ksi)
#pragma unroll
            for (int mi2 = 0; mi2 < 2; ++mi2) {
                const float* p = xw + (long)(wm * 64 + mi2 * 32 + l31) * 512
                               + k0 + ksi * 16 + l5 * 8;
                f32x4 f0 = *(const f32x4*)p;
                f32x4 f1 = *(const f32x4*)(p + 4);
                bf16x8 o;
                o[0] = (bf16_t)f0[0]; o[1] = (bf16_t)f0[1];
                o[2] = (bf16_t)f0[2]; o[3] = (bf16_t)f0[3];
                o[4] = (bf16_t)f1[0]; o[5] = (bf16_t)f1[1];
                o[6] = (bf16_t)f1[2]; o[7] = (bf16_t)f1[3];
                aw[ksi * 2 + mi2] = o;
            }
#pragma unroll
        for (int ksi = 0; ksi < 4; ++ksi) {
            const int ks = ksi * 16;
#pragma unroll
            for (int ni = 0; ni < 3; ++ni) {
                bf16x8 b = *(const bf16x8*)&lW[swz64(wn * 96 + ni * 32 + l31,
                                                    ks + l5 * 8)];
                acc[0][ni] = __builtin_amdgcn_mfma_f32_32x32x16_bf16(
                    aw[ksi * 2 + 0], b, acc[0][ni], 0, 0, 0);
                acc[1][ni] = __builtin_amdgcn_mfma_f32_32x32x16_bf16(
                    aw[ksi * 2 + 1], b, acc[1][ni], 0, 0, 0);
            }
        }
    };

    // prologue
    stageW(wbuf0, 0);
    __syncthreads();
    // main loop; buffers compile-time via 2-step unroll (rule #20)
#pragma unroll 1
    for (int kc2 = 0; kc2 < 4; ++kc2) {
        const int kc = kc2 * 2;
        stageW(wbuf1, (kc + 1) * 64);
        computeW(wbuf0, kc * 64);
        __syncthreads();
        if (kc + 2 < 8) stageW(wbuf0, (kc + 2) * 64);
        computeW(wbuf1, (kc + 1) * 64);
        __syncthreads();
    }

    // scatter QKV accumulators to LDS.
    // 32x32 C/D layout: col = lane&31, row = (reg&3) + 8*(reg>>2) + 4*(lane>>5)
#pragma unroll
    for (int mi = 0; mi < 2; ++mi) {
#pragma unroll
        for (int ni = 0; ni < 3; ++ni) {
            const int n = wn * 96 + ni * 32 + l31;
            const int g = n >> 6;            // 0=Q 1=K 2=V (wave-uniform)
            const int c = n & 63;
            if (g == 2) {
                // V^T: pack 4 consecutive tokens -> one b64 store
#pragma unroll
                for (int rq = 0; rq < 4; ++rq) {
                    const int tk0 = mi * 32 + 8 * rq + 4 * l5;
                    bf16x4 pk;
                    pk[0] = (bf16_t)acc[mi][ni][rq * 4 + 0];
                    pk[1] = (bf16_t)acc[mi][ni][rq * 4 + 1];
                    pk[2] = (bf16_t)acc[mi][ni][rq * 4 + 2];
                    pk[3] = (bf16_t)acc[mi][ni][rq * 4 + 3];
                    *(bf16x4*)&lVw[swz64(c, tk0)] = pk;
                }
            } else {
#pragma unroll
                for (int r = 0; r < 16; ++r) {
                    const int tk = mi * 32 + (r & 3) + ((r >> 2) << 3) + (l5 << 2);
                    const bf16_t val = (bf16_t)acc[mi][ni][r];
                    if (g == 0) lQw[swz64(tk, c)] = val;
                    else        lKw[swz64(tk, c)] = val;
                }
            }
        }
    }
    __syncthreads();   // all QKV of both windows in LDS

    // ---- attention: wave handles window wm, queries qh..qh+31 ----
    const int lr = lane & 15;
    const int q  = lane >> 4;
    const int qh = wn * 32;
    const float scale = 0.125f;

    f32x4 sA[2][4];
#pragma unroll
    for (int i = 0; i < 2; ++i)
#pragma unroll
        for (int j = 0; j < 4; ++j) sA[i][j] = (f32x4)0.0f;
#pragma unroll
    for (int ks = 0; ks < 64; ks += 32) {
        bf16x8 aq0 = *(const bf16x8*)&lQw[swz64(qh +  0 + lr, ks + q * 8)];
        bf16x8 aq1 = *(const bf16x8*)&lQw[swz64(qh + 16 + lr, ks + q * 8)];
#pragma unroll
        for (int j = 0; j < 4; ++j) {
            bf16x8 bk = *(const bf16x8*)&lKw[swz64(j * 16 + lr, ks + q * 8)];
            sA[0][j] = __builtin_amdgcn_mfma_f32_16x16x32_bf16(aq0, bk, sA[0][j], 0, 0, 0);
            sA[1][j] = __builtin_amdgcn_mfma_f32_16x16x32_bf16(aq1, bk, sA[1][j], 0, 0, 0);
        }
    }

    // softmax: row = qh + i*16 + q*4 + reg, keys = j*16 + lr
    // P overwrites Q's tile: this wave's Q reads above are complete (their
    // results feed sA), and rows qh..qh+31 are wave-private.
#pragma unroll
    for (int i = 0; i < 2; ++i)
#pragma unroll
    for (int reg = 0; reg < 4; ++reg) {
        float m = fmaxf(fmaxf(sA[i][0][reg], sA[i][1][reg]),
                        fmaxf(sA[i][2][reg], sA[i][3][reg]));
#pragma unroll
        for (int d = 1; d < 16; d <<= 1) m = fmaxf(m, __shfl_xor(m, d));
        float p[4];
        float sum = 0.0f;
#pragma unroll
        for (int j = 0; j < 4; ++j) {
            p[j] = __expf((sA[i][j][reg] - m) * scale);
            sum += p[j];
        }
#pragma unroll
        for (int d = 1; d < 16; d <<= 1) sum += __shfl_xor(sum, d);
        const float inv = 1.0f / sum;
        const int row = qh + i * 16 + q * 4 + reg;
#pragma unroll
        for (int j = 0; j < 4; ++j)
            lPw[swz64(row, j * 16 + lr)] = (bf16_t)(p[j] * inv);
    }
    // lPw rows are wave-private; no barrier needed before PV.

    f32x4 o[2][4];
#pragma unroll
    for (int i = 0; i < 2; ++i)
#pragma unroll
        for (int d4 = 0; d4 < 4; ++d4) o[i][d4] = (f32x4)0.0f;
#pragma unroll
    for (int ks = 0; ks < 64; ks += 32) {
        bf16x8 ap0 = *(const bf16x8*)&lPw[swz64(qh +  0 + lr, ks + q * 8)];
        bf16x8 ap1 = *(const bf16x8*)&lPw[swz64(qh + 16 + lr, ks + q * 8)];
#pragma unroll
        for (int d4 = 0; d4 < 4; ++d4) {
            bf16x8 bv = *(const bf16x8*)&lVw[swz64(d4 * 16 + lr, ks + q * 8)];
            o[0][d4] = __builtin_amdgcn_mfma_f32_16x16x32_bf16(ap0, bv, o[0][d4], 0, 0, 0);
            o[1][d4] = __builtin_amdgcn_mfma_f32_16x16x32_bf16(ap1, bv, o[1][d4], 0, 0, 0);
        }
    }

    // ---- write O to global ao in proj-matrix coordinates ----
    const int wid = wid0 + wm;
    const int bb  = wid >> 6;
    const int nw  = wid & 63;
    bf16_t* aop = ao + ((long)bb * 4096 + (long)h * 512 + nw * 8) * 512;
#pragma unroll
    for (int i = 0; i < 2; ++i)
#pragma unroll
    for (int d4 = 0; d4 < 4; ++d4)
#pragma unroll
    for (int reg = 0; reg < 4; ++reg) {
        const int wr = qh + i * 16 + q * 4 + reg;
        aop[(long)(wr >> 3) * 512 + (wr & 7) * 64 + d4 * 16 + lr] =
            (bf16_t)o[i][d4][reg];
    }
}

// ---------------------------------------------------------------------------
// out[M,N] = ao[M,K] @ pT[N,K]^T + bias, m97 structure: global_load_lds
// staging (pre-swizzled source, swizzled conflict-free ds_read_b128),
// 128x128 tile, BK=64, 32 KB LDS.  (unchanged this round)
// ---------------------------------------------------------------------------
__global__ __launch_bounds__(256) void gemm2_kernel(
    const bf16_t* __restrict__ A,    // [M,K] = ao
    const bf16_t* __restrict__ Bt,   // [N,K] = pT
    const float*  __restrict__ bias, // [N]
    float* __restrict__ C,           // [M,N]
    int M, int N, int K)
{
    __shared__ bf16_t lA[8192];      // [128][64] swizzled
    __shared__ bf16_t lB[8192];

    const int tid  = threadIdx.x;
    const int wave = tid >> 6;
    const int lane = tid & 63;
    const int wm   = wave >> 1;
    const int wn   = wave & 1;
    const int lr   = lane & 15;
    const int q    = lane >> 4;
    const int rlo  = lane >> 3;
    const int ch   = (lane & 7) ^ rlo;

    const int id  = blockIdx.x;       // 0..1023
    const int xcd = id & 7;
    const int s   = id >> 3;          // 0..127
    const int bm  = xcd * 32 + (s >> 2);
    const int bn  = s & 3;

    const long arow0 = (long)bm * 128;
    const long brow0 = (long)bn * 128;

    f32x4 acc[4][4];
#pragma unroll
    for (int i = 0; i < 4; ++i)
#pragma unroll
        for (int j = 0; j < 4; ++j) acc[i][j] = (f32x4)0.0f;

    const int nk = K / 64;
    for (int kt = 0; kt < nk; ++kt) {
        const long k0 = kt * 64;
#pragma unroll
        for (int p = 0; p < 4; ++p) {
            const int rb = wave * 4 + p;              // 0..15
            const int r  = rb * 8 + rlo;              // 0..127
            GLOAD_LDS16(A  + (arow0 + r) * (long)K + k0 + ch * 8, lA + rb * 512);
            GLOAD_LDS16(Bt + (brow0 + r) * (long)K + k0 + ch * 8, lB + rb * 512);
        }
        __syncthreads();
#pragma unroll
        for (int ks = 0; ks < 64; ks += 32) {
            bf16x8 af[4], bf[4];
#pragma unroll
            for (int i = 0; i < 4; ++i)
                af[i] = *(const bf16x8*)&lA[swz64(wm * 64 + i * 16 + lr, ks + q * 8)];
#pragma unroll
            for (int j = 0; j < 4; ++j)
                bf[j] = *(const bf16x8*)&lB[swz64(wn * 64 + j * 16 + lr, ks + q * 8)];
#pragma unroll
            for (int i = 0; i < 4; ++i)
#pragma unroll
                for (int j = 0; j < 4; ++j)
                    acc[i][j] = __builtin_amdgcn_mfma_f32_16x16x32_bf16(
                        af[i], bf[j], acc[i][j], 0, 0, 0);
        }
        __syncthreads();
    }

    // epilogue: C/D layout col=lane&15, row=(lane>>4)*4+reg
#pragma unroll
    for (int i = 0; i < 4; ++i) {
        const long r = arow0 + wm * 64 + i * 16 + q * 4;
#pragma unroll
        for (int j = 0; j < 4; ++j) {
            const long c = brow0 + wn * 64 + j * 16 + lr;
            const float bv2 = bias[c];
#pragma unroll
            for (int reg = 0; reg < 4; ++reg) {
                C[(r + reg) * N + c] = acc[i][j][reg] + bv2;
            }
        }
    }
}

// ---------------------------------------------------------------------------
extern "C" void kernel_launch(void* const* d_in, const int* in_sizes, int n_in,
                              void* d_out, int out_size, void* d_ws, size_t ws_size,
                              hipStream_t stream)
{
    (void)in_sizes; (void)n_in; (void)out_size; (void)ws_size;
    const float* x     = (const float*)d_in[0];  // [8,64,64,512] fp32
    const float* wqkv  = (const float*)d_in[1];  // [512,1536] fp32
    const float* wproj = (const float*)d_in[2];  // [512,512] fp32
    const float* bproj = (const float*)d_in[3];  // [512] fp32
    float* out = (float*)d_out;                  // [8,64,64,512] fp32

    // workspace: wT 1.5 MB + pT 0.5 MB + ao 32 MB = 34 MB
    bf16_t* wT = (bf16_t*)d_ws;                  // [1536][512]
    bf16_t* pT = wT + (size_t)1536 * 512;        // [512][512]
    bf16_t* ao = pT + (size_t)512 * 512;         // [32768][512] proj layout

    transpose_cast_kernel<<<dim3(48, 16), 256, 0, stream>>>(wqkv, wT, 512, 1536);
    transpose_cast_kernel<<<dim3(16, 16), 256, 0, stream>>>(wproj, pT, 512, 512);

    qkv_attn_kernel<<<2048, 256, 0, stream>>>(x, wT, ao);

    gemm2_kernel<<<1024, 256, 0, stream>>>(
        ao, pT, bproj, out, 32768, 512, 512);
}

// Round 5
// 243.007 us; speedup vs baseline: 1.2002x; 1.2002x over previous
//
#include <hip/hip_runtime.h>
#include <hip/hip_bf16.h>

typedef __bf16 bf16_t;
typedef __bf16 bf16x4 __attribute__((ext_vector_type(4)));
typedef __bf16 bf16x8 __attribute__((ext_vector_type(8)));
typedef float f32x4 __attribute__((ext_vector_type(4)));
typedef float f32x16 __attribute__((ext_vector_type(16)));

// 16B global -> LDS DMA (wave-uniform LDS base, dest = base + lane*16)
#define GLOAD_LDS16(gp, lp) __builtin_amdgcn_global_load_lds( \
    (const __attribute__((address_space(1))) void*)(gp),      \
    (__attribute__((address_space(3))) void*)(lp), 16, 0, 0)

// element index into a [rows][64] bf16 tile with XOR swizzle:
// byte ^= ((row&7)<<4)  <=>  element col ^= ((row&7)<<3)
__device__ __forceinline__ int swz64(int row, int col) {
    return row * 64 + (col ^ ((row & 7) << 3));
}

// ---------------------------------------------------------------------------
// fp32 src[R][C] -> bf16 dst[C][R]
// ---------------------------------------------------------------------------
__global__ __launch_bounds__(256) void transpose_cast_kernel(
    const float* __restrict__ src, bf16_t* __restrict__ dst, int R, int C)
{
    __shared__ float tile[32][33];
    const int bx = blockIdx.x;  // C/32
    const int by = blockIdx.y;  // R/32
    const int t  = threadIdx.x;
    const int i0 = t >> 5;      // 0..7
    const int j  = t & 31;
#pragma unroll
    for (int p = 0; p < 4; ++p) {
        int i = i0 + p * 8;
        tile[i][j] = src[(long)(by * 32 + i) * C + bx * 32 + j];
    }
    __syncthreads();
#pragma unroll
    for (int p = 0; p < 4; ++p) {
        int i = i0 + p * 8;
        dst[(long)(bx * 32 + i) * R + by * 32 + j] = (bf16_t)tile[j][i];
    }
}

// ---------------------------------------------------------------------------
// fp32 -> bf16 cast, vectorized grid-stride.
// ---------------------------------------------------------------------------
__global__ __launch_bounds__(256) void cast_x_kernel(
    const float* __restrict__ src, bf16_t* __restrict__ dst, long n8)
{
    long i = (long)blockIdx.x * blockDim.x + threadIdx.x;
    const long stride = (long)gridDim.x * blockDim.x;
    for (; i < n8; i += stride) {
        const float* p = src + i * 8;
        f32x4 f0 = *(const f32x4*)p;
        f32x4 f1 = *(const f32x4*)(p + 4);
        bf16x8 o;
        o[0] = (bf16_t)f0[0]; o[1] = (bf16_t)f0[1];
        o[2] = (bf16_t)f0[2]; o[3] = (bf16_t)f0[3];
        o[4] = (bf16_t)f1[0]; o[5] = (bf16_t)f1[1];
        o[6] = (bf16_t)f1[2]; o[7] = (bf16_t)f1[3];
        *(bf16x8*)(dst + i * 8) = o;
    }
}

// ---------------------------------------------------------------------------
// QKV + window attention v5: one block per (window PAIR, head).
// 2048 blocks x 512 thr (8 waves), 48 KB LDS -> 2 blocks/CU = 4 waves/SIMD
// (2x v3's TLP). GEMM M=128, N=192, K=512; wave grid 4x2, tile 32x96,
// acc = 3 x f32x16 (48 VGPR). Per chunk:
//   stageW(next)           10->3 global_load_lds/thread (W only, 24 KB)
//   loadx(next -> regs)    4 x dwordx4 bf16 (prefetch; NOT JIT like v4)
//   compute(cur)           12 ds_read_b128 + 12 MFMA 32x32x16 per wave
//   __syncthreads
// x never touches LDS; W is the only staged operand.
// ---------------------------------------------------------------------------
__global__ __launch_bounds__(512, 4) void qkv_attn_kernel(
    const bf16_t* __restrict__ xb,    // [32768][512] bf16 (pre-cast x)
    const bf16_t* __restrict__ wT,    // [1536][512]  (= w_qkv^T, bf16)
    bf16_t* __restrict__ ao)          // [32768][512] bf16, proj layout
{
    __shared__ bf16_t arena[24576];        // 48 KB
    bf16_t* const wbuf0 = arena;           // [192][64] swizzled
    bf16_t* const wbuf1 = arena + 12288;

    // XCD swizzle: a pair's 8 head-blocks on one XCD, pairs contiguous.
    const int id   = blockIdx.x;           // 0..2047
    const int xcd  = id & 7;
    const int s    = id >> 3;              // 0..255
    const int pr   = xcd * 32 + (s >> 3);  // window pair 0..255
    const int h    = s & 7;
    const int wid0 = pr * 2;

    const bf16_t* xw = xb + (long)wid0 * 64 * 512;

    const int t    = threadIdx.x;
    const int wv   = t >> 6;               // 0..7
    const int lane = t & 63;
    const int wr   = wv >> 1;              // 0..3: M rows wr*32..+31
    const int wc   = wv & 1;               // 0..1: N cols wc*96..+95
    const int l31  = lane & 31;
    const int l5   = lane >> 5;
    const int rlo  = lane >> 3;            // row-within-8-block
    const int ch   = (lane & 7) ^ rlo;     // pre-swizzled source chunk

    // stage W chunk [192][64] via DMA, inverse-swizzled source (3/thread)
    auto stageW = [&](bf16_t* buf, int k0) {
#pragma unroll
        for (int j = 0; j < 3; ++j) {
            const int rb = wv * 3 + j;                 // 0..23
            const int nr = rb * 8 + rlo;               // 0..191
            const int grow = ((nr >> 6) << 9) + h * 64 + (nr & 63);
            GLOAD_LDS16(wT + (long)grow * 512 + k0 + ch * 8, buf + rb * 512);
        }
    };
    // A-frag prefetch: 4 x bf16x8 from global (A layout: row=l&31, k=(l>>5)*8+e)
    auto loadx = [&](bf16x8* a, int k0) {
        const bf16_t* rp = xw + (long)(wr * 32 + l31) * 512 + k0 + l5 * 8;
#pragma unroll
        for (int ksi = 0; ksi < 4; ++ksi)
            a[ksi] = *(const bf16x8*)(rp + ksi * 16);
    };

    f32x16 acc[3];
#pragma unroll
    for (int ni = 0; ni < 3; ++ni) acc[ni] = (f32x16)0.0f;

    auto compute = [&](const bf16x8* a, const bf16_t* lW) {
#pragma unroll
        for (int ksi = 0; ksi < 4; ++ksi) {
            const int ks = ksi * 16;
#pragma unroll
            for (int ni = 0; ni < 3; ++ni) {
                bf16x8 b = *(const bf16x8*)&lW[swz64(wc * 96 + ni * 32 + l31,
                                                    ks + l5 * 8)];
                acc[ni] = __builtin_amdgcn_mfma_f32_32x32x16_bf16(
                    a[ksi], b, acc[ni], 0, 0, 0);
            }
        }
    };

    bf16x8 aC[4], aN[4];
    // prologue
    stageW(wbuf0, 0);
    loadx(aC, 0);
    __syncthreads();
    // main loop; buffers/regs compile-time via 2-step unroll (rule #20)
#pragma unroll 1
    for (int kc2 = 0; kc2 < 4; ++kc2) {
        const int kc = kc2 * 2;
        stageW(wbuf1, (kc + 1) * 64);
        loadx(aN, (kc + 1) * 64);
        compute(aC, wbuf0);
        __syncthreads();
        if (kc2 < 3) {
            stageW(wbuf0, (kc + 2) * 64);
            loadx(aC, (kc + 2) * 64);
        }
        compute(aN, wbuf1);
        __syncthreads();
    }

    // ---- scatter QKV accumulators to the attention overlay ----
    // 32x32 C/D: col = l31, row = (r&3) + 8*(r>>2) + 4*l5   (+ wr*32)
    // overlay: win*12288 + {Q:0, K:4096, V^T:8192}; all [64][64] swizzled
    const int swin = wr >> 1;                    // window of this wave's rows
    bf16_t* const sQ = arena + swin * 12288;
    bf16_t* const sK = sQ + 4096;
    bf16_t* const sV = sQ + 8192;
#pragma unroll
    for (int ni = 0; ni < 3; ++ni) {
        const int n = wc * 96 + ni * 32 + l31;
        const int g = n >> 6;                    // 0=Q 1=K 2=V (wave-uniform)
        const int c = n & 63;
        if (g == 2) {
            // V^T: pack 4 consecutive tokens -> one b64 store
#pragma unroll
            for (int rq = 0; rq < 4; ++rq) {
                const int tl0 = (wr & 1) * 32 + 8 * rq + 4 * l5;
                bf16x4 pk;
                pk[0] = (bf16_t)acc[ni][rq * 4 + 0];
                pk[1] = (bf16_t)acc[ni][rq * 4 + 1];
                pk[2] = (bf16_t)acc[ni][rq * 4 + 2];
                pk[3] = (bf16_t)acc[ni][rq * 4 + 3];
                *(bf16x4*)&sV[swz64(c, tl0)] = pk;
            }
        } else {
#pragma unroll
            for (int r = 0; r < 16; ++r) {
                const int tl = (wr & 1) * 32 + (r & 3) + ((r >> 2) << 3) + (l5 << 2);
                const bf16_t val = (bf16_t)acc[ni][r];
                if (g == 0) sQ[swz64(tl, c)] = val;
                else        sK[swz64(tl, c)] = val;
            }
        }
    }
    __syncthreads();   // all QKV of both windows in LDS

    // ---- attention: wave wv -> window wv>>2, queries (wv&3)*16..+15 ----
    const int win = wv >> 2;
    const int qb  = wv & 3;
    bf16_t* const lQ = arena + win * 12288;
    bf16_t* const lK = lQ + 4096;
    bf16_t* const lV = lQ + 8192;
    bf16_t* const lP = lQ;                 // P reuses Q (wave-own rows only)

    const int lr = lane & 15;
    const int q  = lane >> 4;
    const float scale = 0.125f;

    f32x4 sA[4];
#pragma unroll
    for (int j = 0; j < 4; ++j) sA[j] = (f32x4)0.0f;
#pragma unroll
    for (int ks = 0; ks < 64; ks += 32) {
        bf16x8 aq = *(const bf16x8*)&lQ[swz64(qb * 16 + lr, ks + q * 8)];
#pragma unroll
        for (int j = 0; j < 4; ++j) {
            bf16x8 bk = *(const bf16x8*)&lK[swz64(j * 16 + lr, ks + q * 8)];
            sA[j] = __builtin_amdgcn_mfma_f32_16x16x32_bf16(aq, bk, sA[j], 0, 0, 0);
        }
    }

    // softmax: row = qb*16 + q*4 + reg, keys = j*16 + lr
#pragma unroll
    for (int reg = 0; reg < 4; ++reg) {
        float m = fmaxf(fmaxf(sA[0][reg], sA[1][reg]),
                        fmaxf(sA[2][reg], sA[3][reg]));
#pragma unroll
        for (int d = 1; d < 16; d <<= 1) m = fmaxf(m, __shfl_xor(m, d));
        float p[4];
        float sum = 0.0f;
#pragma unroll
        for (int j = 0; j < 4; ++j) {
            p[j] = __expf((sA[j][reg] - m) * scale);
            sum += p[j];
        }
#pragma unroll
        for (int d = 1; d < 16; d <<= 1) sum += __shfl_xor(sum, d);
        const float inv = 1.0f / sum;
        const int row = qb * 16 + q * 4 + reg;
#pragma unroll
        for (int j = 0; j < 4; ++j)
            lP[swz64(row, j * 16 + lr)] = (bf16_t)(p[j] * inv);
    }
    // lP rows are wave-private; no barrier needed before PV.

    f32x4 o[4];
#pragma unroll
    for (int d4 = 0; d4 < 4; ++d4) o[d4] = (f32x4)0.0f;
#pragma unroll
    for (int ks = 0; ks < 64; ks += 32) {
        bf16x8 ap = *(const bf16x8*)&lP[swz64(qb * 16 + lr, ks + q * 8)];
#pragma unroll
        for (int d4 = 0; d4 < 4; ++d4) {
            bf16x8 bv = *(const bf16x8*)&lV[swz64(d4 * 16 + lr, ks + q * 8)];
            o[d4] = __builtin_amdgcn_mfma_f32_16x16x32_bf16(ap, bv, o[d4], 0, 0, 0);
        }
    }

    // ---- write O to global ao in proj-matrix coordinates ----
    const int wid = wid0 + win;
    const int bb  = wid >> 6;
    const int nw  = wid & 63;
    bf16_t* aop = ao + ((long)bb * 4096 + (long)h * 512 + nw * 8) * 512;
#pragma unroll
    for (int d4 = 0; d4 < 4; ++d4)
#pragma unroll
    for (int reg = 0; reg < 4; ++reg) {
        const int tok = qb * 16 + q * 4 + reg;
        aop[(long)(tok >> 3) * 512 + (tok & 7) * 64 + d4 * 16 + lr] =
            (bf16_t)o[d4][reg];
    }
}

// ---------------------------------------------------------------------------
// out[M,N] = ao[M,K] @ pT[N,K]^T + bias, m97 structure: global_load_lds
// staging (pre-swizzled source, swizzled conflict-free ds_read_b128),
// 128x128 tile, BK=64, 32 KB LDS.  (unchanged this round)
// ---------------------------------------------------------------------------
__global__ __launch_bounds__(256) void gemm2_kernel(
    const bf16_t* __restrict__ A,    // [M,K] = ao
    const bf16_t* __restrict__ Bt,   // [N,K] = pT
    const float*  __restrict__ bias, // [N]
    float* __restrict__ C,           // [M,N]
    int M, int N, int K)
{
    __shared__ bf16_t lA[8192];      // [128][64] swizzled
    __shared__ bf16_t lB[8192];

    const int tid  = threadIdx.x;
    const int wave = tid >> 6;
    const int lane = tid & 63;
    const int wm   = wave >> 1;
    const int wn   = wave & 1;
    const int lr   = lane & 15;
    const int q    = lane >> 4;
    const int rlo  = lane >> 3;
    const int ch   = (lane & 7) ^ rlo;

    const int id  = blockIdx.x;       // 0..1023
    const int xcd = id & 7;
    const int s   = id >> 3;          // 0..127
    const int bm  = xcd * 32 + (s >> 2);
    const int bn  = s & 3;

    const long arow0 = (long)bm * 128;
    const long brow0 = (long)bn * 128;

    f32x4 acc[4][4];
#pragma unroll
    for (int i = 0; i < 4; ++i)
#pragma unroll
        for (int j = 0; j < 4; ++j) acc[i][j] = (f32x4)0.0f;

    const int nk = K / 64;
    for (int kt = 0; kt < nk; ++kt) {
        const long k0 = kt * 64;
#pragma unroll
        for (int p = 0; p < 4; ++p) {
            const int rb = wave * 4 + p;              // 0..15
            const int r  = rb * 8 + rlo;              // 0..127
            GLOAD_LDS16(A  + (arow0 + r) * (long)K + k0 + ch * 8, lA + rb * 512);
            GLOAD_LDS16(Bt + (brow0 + r) * (long)K + k0 + ch * 8, lB + rb * 512);
        }
        __syncthreads();
#pragma unroll
        for (int ks = 0; ks < 64; ks += 32) {
            bf16x8 af[4], bf[4];
#pragma unroll
            for (int i = 0; i < 4; ++i)
                af[i] = *(const bf16x8*)&lA[swz64(wm * 64 + i * 16 + lr, ks + q * 8)];
#pragma unroll
            for (int j = 0; j < 4; ++j)
                bf[j] = *(const bf16x8*)&lB[swz64(wn * 64 + j * 16 + lr, ks + q * 8)];
#pragma unroll
            for (int i = 0; i < 4; ++i)
#pragma unroll
                for (int j = 0; j < 4; ++j)
                    acc[i][j] = __builtin_amdgcn_mfma_f32_16x16x32_bf16(
                        af[i], bf[j], acc[i][j], 0, 0, 0);
        }
        __syncthreads();
    }

    // epilogue: C/D layout col=lane&15, row=(lane>>4)*4+reg
#pragma unroll
    for (int i = 0; i < 4; ++i) {
        const long r = arow0 + wm * 64 + i * 16 + q * 4;
#pragma unroll
        for (int j = 0; j < 4; ++j) {
            const long c = brow0 + wn * 64 + j * 16 + lr;
            const float bv2 = bias[c];
#pragma unroll
            for (int reg = 0; reg < 4; ++reg) {
                C[(r + reg) * N + c] = acc[i][j][reg] + bv2;
            }
        }
    }
}

// ---------------------------------------------------------------------------
extern "C" void kernel_launch(void* const* d_in, const int* in_sizes, int n_in,
                              void* d_out, int out_size, void* d_ws, size_t ws_size,
                              hipStream_t stream)
{
    (void)in_sizes; (void)n_in; (void)out_size;
    const float* x     = (const float*)d_in[0];  // [8,64,64,512] fp32
    const float* wqkv  = (const float*)d_in[1];  // [512,1536] fp32
    const float* wproj = (const float*)d_in[2];  // [512,512] fp32
    const float* bproj = (const float*)d_in[3];  // [512] fp32
    float* out = (float*)d_out;                  // [8,64,64,512] fp32

    // workspace: wT 1.5 MB + pT 0.5 MB + ao 32 MB (+ xb 32 MB when it fits)
    bf16_t* wT = (bf16_t*)d_ws;                  // [1536][512]
    bf16_t* pT = wT + (size_t)1536 * 512;        // [512][512]
    bf16_t* ao = pT + (size_t)512 * 512;         // [32768][512] proj layout

    // x pre-cast scratch: prefer workspace; fall back to d_out's first 32 MB
    // (fully overwritten by gemm2 afterwards, stream-ordered).
    const size_t base_elems = (size_t)1536 * 512 + (size_t)512 * 512
                            + (size_t)32768 * 512;
    const size_t xb_elems   = (size_t)32768 * 512;
    bf16_t* xb = (ws_size >= (base_elems + xb_elems) * sizeof(bf16_t))
               ? (ao + xb_elems)
               : (bf16_t*)d_out;

    transpose_cast_kernel<<<dim3(48, 16), 256, 0, stream>>>(wqkv, wT, 512, 1536);
    transpose_cast_kernel<<<dim3(16, 16), 256, 0, stream>>>(wproj, pT, 512, 512);
    cast_x_kernel<<<2048, 256, 0, stream>>>(x, xb, (long)32768 * 512 / 8);

    qkv_attn_kernel<<<2048, 512, 0, stream>>>(xb, wT, ao);

    gemm2_kernel<<<1024, 256, 0, stream>>>(
        ao, pT, bproj, out, 32768, 512, 512);
}

// Round 6
// 209.782 us; speedup vs baseline: 1.3903x; 1.1584x over previous
//
#include <hip/hip_runtime.h>
#include <hip/hip_bf16.h>

typedef __bf16 bf16_t;
typedef __bf16 bf16x4 __attribute__((ext_vector_type(4)));
typedef __bf16 bf16x8 __attribute__((ext_vector_type(8)));
typedef float f32x4 __attribute__((ext_vector_type(4)));
typedef float f32x16 __attribute__((ext_vector_type(16)));

// 16B global -> LDS DMA (wave-uniform LDS base, dest = base + lane*16)
#define GLOAD_LDS16(gp, lp) __builtin_amdgcn_global_load_lds( \
    (const __attribute__((address_space(1))) void*)(gp),      \
    (__attribute__((address_space(3))) void*)(lp), 16, 0, 0)

// counted vmem wait (T4): N = loads allowed to stay in flight. Literal only.
#define VMCNT(n) asm volatile("s_waitcnt vmcnt(" #n ")" ::: "memory")
#define SCHED_FENCE() __builtin_amdgcn_sched_barrier(0)
#define BARRIER() __builtin_amdgcn_s_barrier()

// element index into a [rows][64] bf16 tile with XOR swizzle:
// byte ^= ((row&7)<<4)  <=>  element col ^= ((row&7)<<3)
__device__ __forceinline__ int swz64(int row, int col) {
    return row * 64 + (col ^ ((row & 7) << 3));
}

// ---------------------------------------------------------------------------
// fp32 src[R][C] -> bf16 dst[C][R]
// ---------------------------------------------------------------------------
__global__ __launch_bounds__(256) void transpose_cast_kernel(
    const float* __restrict__ src, bf16_t* __restrict__ dst, int R, int C)
{
    __shared__ float tile[32][33];
    const int bx = blockIdx.x;  // C/32
    const int by = blockIdx.y;  // R/32
    const int t  = threadIdx.x;
    const int i0 = t >> 5;      // 0..7
    const int j  = t & 31;
#pragma unroll
    for (int p = 0; p < 4; ++p) {
        int i = i0 + p * 8;
        tile[i][j] = src[(long)(by * 32 + i) * C + bx * 32 + j];
    }
    __syncthreads();
#pragma unroll
    for (int p = 0; p < 4; ++p) {
        int i = i0 + p * 8;
        dst[(long)(bx * 32 + i) * R + by * 32 + j] = (bf16_t)tile[j][i];
    }
}

// ---------------------------------------------------------------------------
// fp32 -> bf16 cast, vectorized grid-stride.
// ---------------------------------------------------------------------------
__global__ __launch_bounds__(256) void cast_x_kernel(
    const float* __restrict__ src, bf16_t* __restrict__ dst, long n8)
{
    long i = (long)blockIdx.x * blockDim.x + threadIdx.x;
    const long stride = (long)gridDim.x * blockDim.x;
    for (; i < n8; i += stride) {
        const float* p = src + i * 8;
        f32x4 f0 = *(const f32x4*)p;
        f32x4 f1 = *(const f32x4*)(p + 4);
        bf16x8 o;
        o[0] = (bf16_t)f0[0]; o[1] = (bf16_t)f0[1];
        o[2] = (bf16_t)f0[2]; o[3] = (bf16_t)f0[3];
        o[4] = (bf16_t)f1[0]; o[5] = (bf16_t)f1[1];
        o[6] = (bf16_t)f1[2]; o[7] = (bf16_t)f1[3];
        *(bf16x8*)(dst + i * 8) = o;
    }
}

// ---------------------------------------------------------------------------
// QKV + window attention v6 = v3 structure (session best, 88.4 us) with the
// drain-barrier replaced by counted-vmcnt pipeline (T4):
//   stage(next buf)  [10 DMA]
//   s_waitcnt vmcnt(10)   <- waits CURRENT buf only; next's 10 stay in flight
//   s_barrier
//   setprio(1); compute(cur); setprio(0)
//   s_barrier             <- reads of cur done before next overwrite
// Plus V^T b64-pack scatter (proven v4/v5, halves bank conflicts).
// 2048 blocks x 256 thr, 80 KB LDS -> 2 blocks/CU.
// ---------------------------------------------------------------------------
__global__ __launch_bounds__(256, 2) void qkv_attn_kernel(
    const bf16_t* __restrict__ xb,    // [32768][512] bf16 (pre-cast x)
    const bf16_t* __restrict__ wT,    // [1536][512]  (= w_qkv^T, bf16)
    bf16_t* __restrict__ ao)          // [32768][512] bf16, proj layout
{
    __shared__ bf16_t arena[40960];        // 80 KB
    bf16_t* const buf0 = arena;            // [lX 128x64 | lW 192x64]
    bf16_t* const buf1 = arena + 20480;

    // XCD swizzle: a pair's 8 head-blocks on one XCD, pairs contiguous.
    const int id   = blockIdx.x;           // 0..2047
    const int xcd  = id & 7;
    const int s    = id >> 3;              // 0..255
    const int pr   = xcd * 32 + (s >> 3);  // window pair 0..255
    const int h    = s & 7;
    const int wid0 = pr * 2;

    const bf16_t* xw = xb + (long)wid0 * 64 * 512;

    const int t    = threadIdx.x;
    const int wv   = t >> 6;
    const int lane = t & 63;
    const int wm   = wv >> 1;              // row half == window index
    const int wn   = wv & 1;               // col half (GEMM) / query half (attn)
    const int l31  = lane & 31;
    const int l5   = lane >> 5;
    const int rlo  = lane >> 3;            // row-within-8-block
    const int ch   = (lane & 7) ^ rlo;     // pre-swizzled source chunk

    // attention overlay (valid after post-GEMM barrier)
    bf16_t* const lQw = arena +     0 + wm * 12288;  // [64][64]
    bf16_t* const lKw = arena +  4096 + wm * 12288;  // [64][64]
    bf16_t* const lVw = arena +  8192 + wm * 12288;  // V^T [d][k]
    bf16_t* const lPw = arena + 24576 + wm * 4096;   // [64][64]

    // stage chunk k0 into buf: x 16 row-blocks (4/wave), W 24 row-blocks (6/wave)
    auto stage = [&](bf16_t* buf, int k0) {
#pragma unroll
        for (int p = 0; p < 4; ++p) {
            const int rb = wv * 4 + p;                 // 0..15
            GLOAD_LDS16(xw + (long)(rb * 8 + rlo) * 512 + k0 + ch * 8,
                        buf + rb * 512);
        }
#pragma unroll
        for (int j = 0; j < 6; ++j) {
            const int rb = wv * 6 + j;                 // 0..23
            const int nr = rb * 8 + rlo;               // 0..191
            const int grow = ((nr >> 6) << 9) + h * 64 + (nr & 63);
            GLOAD_LDS16(wT + (long)grow * 512 + k0 + ch * 8,
                        buf + 8192 + rb * 512);
        }
    };

    f32x16 acc[2][3];
#pragma unroll
    for (int mi = 0; mi < 2; ++mi)
#pragma unroll
        for (int ni = 0; ni < 3; ++ni) acc[mi][ni] = (f32x16)0.0f;

    auto compute = [&](const bf16_t* lX, const bf16_t* lW) {
        __builtin_amdgcn_s_setprio(1);
#pragma unroll
        for (int ks = 0; ks < 64; ks += 16) {
            bf16x8 a0 = *(const bf16x8*)&lX[swz64(wm * 64 +  0 + l31, ks + l5 * 8)];
            bf16x8 a1 = *(const bf16x8*)&lX[swz64(wm * 64 + 32 + l31, ks + l5 * 8)];
#pragma unroll
            for (int ni = 0; ni < 3; ++ni) {
                bf16x8 b = *(const bf16x8*)&lW[swz64(wn * 96 + ni * 32 + l31, ks + l5 * 8)];
                acc[0][ni] = __builtin_amdgcn_mfma_f32_32x32x16_bf16(a0, b, acc[0][ni], 0, 0, 0);
                acc[1][ni] = __builtin_amdgcn_mfma_f32_32x32x16_bf16(a1, b, acc[1][ni], 0, 0, 0);
            }
        }
        __builtin_amdgcn_s_setprio(0);
    };

    // ---- pipelined K-loop: counted vmcnt, no drain in steady state ----
    stage(buf0, 0);                              // out = 10 {buf0}
#pragma unroll 1
    for (int kc2 = 0; kc2 < 4; ++kc2) {
        const int kc = kc2 * 2;
        stage(buf1, (kc + 1) * 64);              // out = 20
        VMCNT(10);                               // buf0 staged; buf1 in flight
        SCHED_FENCE();
        BARRIER();
        compute(buf0, buf0 + 8192);
        SCHED_FENCE();
        BARRIER();                               // all reads of buf0 done
        if (kc2 < 3) {
            stage(buf0, (kc + 2) * 64);          // out = 20
            VMCNT(10);                           // buf1 staged; buf0' in flight
        } else {
            VMCNT(0);                            // final: drain
        }
        SCHED_FENCE();
        BARRIER();
        compute(buf1, buf1 + 8192);
        SCHED_FENCE();
        BARRIER();
    }

    // scatter QKV accumulators to LDS.
    // 32x32 C/D layout: col = lane&31, row = (reg&3) + 8*(reg>>2) + 4*(lane>>5)
#pragma unroll
    for (int mi = 0; mi < 2; ++mi) {
#pragma unroll
        for (int ni = 0; ni < 3; ++ni) {
            const int n = wn * 96 + ni * 32 + l31;
            const int g = n >> 6;            // 0=Q 1=K 2=V (wave-uniform)
            const int c = n & 63;
            if (g == 2) {
                // V^T: pack 4 consecutive tokens -> one b64 store
#pragma unroll
                for (int rq = 0; rq < 4; ++rq) {
                    const int tk0 = mi * 32 + 8 * rq + 4 * l5;
                    bf16x4 pk;
                    pk[0] = (bf16_t)acc[mi][ni][rq * 4 + 0];
                    pk[1] = (bf16_t)acc[mi][ni][rq * 4 + 1];
                    pk[2] = (bf16_t)acc[mi][ni][rq * 4 + 2];
                    pk[3] = (bf16_t)acc[mi][ni][rq * 4 + 3];
                    *(bf16x4*)&lVw[swz64(c, tk0)] = pk;
                }
            } else {
#pragma unroll
                for (int r = 0; r < 16; ++r) {
                    const int tk = mi * 32 + (r & 3) + ((r >> 2) << 3) + (l5 << 2);
                    const bf16_t val = (bf16_t)acc[mi][ni][r];
                    if (g == 0) lQw[swz64(tk, c)] = val;
                    else        lKw[swz64(tk, c)] = val;
                }
            }
        }
    }
    __syncthreads();   // all QKV of both windows in LDS

    // ---- attention: wave handles window wm, queries qh..qh+31 ----
    const int lr = lane & 15;
    const int q  = lane >> 4;
    const int qh = wn * 32;
    const float scale = 0.125f;

    f32x4 sA[2][4];
#pragma unroll
    for (int i = 0; i < 2; ++i)
#pragma unroll
        for (int j = 0; j < 4; ++j) sA[i][j] = (f32x4)0.0f;
#pragma unroll
    for (int ks = 0; ks < 64; ks += 32) {
        bf16x8 aq0 = *(const bf16x8*)&lQw[swz64(qh +  0 + lr, ks + q * 8)];
        bf16x8 aq1 = *(const bf16x8*)&lQw[swz64(qh + 16 + lr, ks + q * 8)];
#pragma unroll
        for (int j = 0; j < 4; ++j) {
            bf16x8 bk = *(const bf16x8*)&lKw[swz64(j * 16 + lr, ks + q * 8)];
            sA[0][j] = __builtin_amdgcn_mfma_f32_16x16x32_bf16(aq0, bk, sA[0][j], 0, 0, 0);
            sA[1][j] = __builtin_amdgcn_mfma_f32_16x16x32_bf16(aq1, bk, sA[1][j], 0, 0, 0);
        }
    }

    // softmax: row = qh + i*16 + q*4 + reg, keys = j*16 + lr
#pragma unroll
    for (int i = 0; i < 2; ++i)
#pragma unroll
    for (int reg = 0; reg < 4; ++reg) {
        float m = fmaxf(fmaxf(sA[i][0][reg], sA[i][1][reg]),
                        fmaxf(sA[i][2][reg], sA[i][3][reg]));
#pragma unroll
        for (int d = 1; d < 16; d <<= 1) m = fmaxf(m, __shfl_xor(m, d));
        float p[4];
        float sum = 0.0f;
#pragma unroll
        for (int j = 0; j < 4; ++j) {
            p[j] = __expf((sA[i][j][reg] - m) * scale);
            sum += p[j];
        }
#pragma unroll
        for (int d = 1; d < 16; d <<= 1) sum += __shfl_xor(sum, d);
        const float inv = 1.0f / sum;
        const int row = qh + i * 16 + q * 4 + reg;
#pragma unroll
        for (int j = 0; j < 4; ++j)
            lPw[swz64(row, j * 16 + lr)] = (bf16_t)(p[j] * inv);
    }
    // lPw rows are wave-private; no barrier needed before PV.

    f32x4 o[2][4];
#pragma unroll
    for (int i = 0; i < 2; ++i)
#pragma unroll
        for (int d4 = 0; d4 < 4; ++d4) o[i][d4] = (f32x4)0.0f;
#pragma unroll
    for (int ks = 0; ks < 64; ks += 32) {
        bf16x8 ap0 = *(const bf16x8*)&lPw[swz64(qh +  0 + lr, ks + q * 8)];
        bf16x8 ap1 = *(const bf16x8*)&lPw[swz64(qh + 16 + lr, ks + q * 8)];
#pragma unroll
        for (int d4 = 0; d4 < 4; ++d4) {
            bf16x8 bv = *(const bf16x8*)&lVw[swz64(d4 * 16 + lr, ks + q * 8)];
            o[0][d4] = __builtin_amdgcn_mfma_f32_16x16x32_bf16(ap0, bv, o[0][d4], 0, 0, 0);
            o[1][d4] = __builtin_amdgcn_mfma_f32_16x16x32_bf16(ap1, bv, o[1][d4], 0, 0, 0);
        }
    }

    // ---- write O to global ao in proj-matrix coordinates ----
    const int wid = wid0 + wm;
    const int bb  = wid >> 6;
    const int nw  = wid & 63;
    bf16_t* aop = ao + ((long)bb * 4096 + (long)h * 512 + nw * 8) * 512;
#pragma unroll
    for (int i = 0; i < 2; ++i)
#pragma unroll
    for (int d4 = 0; d4 < 4; ++d4)
#pragma unroll
    for (int reg = 0; reg < 4; ++reg) {
        const int wr = qh + i * 16 + q * 4 + reg;
        aop[(long)(wr >> 3) * 512 + (wr & 7) * 64 + d4 * 16 + lr] =
            (bf16_t)o[i][d4][reg];
    }
}

// ---------------------------------------------------------------------------
// out[M,N] = ao[M,K] @ pT[N,K]^T + bias. 128x128 tile, BK=64, DMA staging,
// now DOUBLE-BUFFERED with counted vmcnt (same T4 discipline as qkv).
// 32 KB LDS (4 x 8 KB), 1024 blocks (4/CU).
// ---------------------------------------------------------------------------
__global__ __launch_bounds__(256) void gemm2_kernel(
    const bf16_t* __restrict__ A,    // [M,K] = ao
    const bf16_t* __restrict__ Bt,   // [N,K] = pT
    const float*  __restrict__ bias, // [N]
    float* __restrict__ C,           // [M,N]
    int M, int N, int K)
{
    __shared__ bf16_t arena[32768];
    bf16_t* const lA0 = arena;
    bf16_t* const lB0 = arena + 8192;
    bf16_t* const lA1 = arena + 16384;
    bf16_t* const lB1 = arena + 24576;

    const int tid  = threadIdx.x;
    const int wave = tid >> 6;
    const int lane = tid & 63;
    const int wm   = wave >> 1;
    const int wn   = wave & 1;
    const int lr   = lane & 15;
    const int q    = lane >> 4;
    const int rlo  = lane >> 3;
    const int ch   = (lane & 7) ^ rlo;

    const int id  = blockIdx.x;       // 0..1023
    const int xcd = id & 7;
    const int s   = id >> 3;          // 0..127
    const int bm  = xcd * 32 + (s >> 2);
    const int bn  = s & 3;

    const long arow0 = (long)bm * 128;
    const long brow0 = (long)bn * 128;

    f32x4 acc[4][4];
#pragma unroll
    for (int i = 0; i < 4; ++i)
#pragma unroll
        for (int j = 0; j < 4; ++j) acc[i][j] = (f32x4)0.0f;

    auto stage = [&](bf16_t* bA, bf16_t* bB, long k0) {
#pragma unroll
        for (int p = 0; p < 4; ++p) {
            const int rb = wave * 4 + p;              // 0..15
            const int r  = rb * 8 + rlo;              // 0..127
            GLOAD_LDS16(A  + (arow0 + r) * (long)K + k0 + ch * 8, bA + rb * 512);
            GLOAD_LDS16(Bt + (brow0 + r) * (long)K + k0 + ch * 8, bB + rb * 512);
        }
    };

    auto compute = [&](const bf16_t* lA, const bf16_t* lB) {
        __builtin_amdgcn_s_setprio(1);
#pragma unroll
        for (int ks = 0; ks < 64; ks += 32) {
            bf16x8 af[4], bf[4];
#pragma unroll
            for (int i = 0; i < 4; ++i)
                af[i] = *(const bf16x8*)&lA[swz64(wm * 64 + i * 16 + lr, ks + q * 8)];
#pragma unroll
            for (int j = 0; j < 4; ++j)
                bf[j] = *(const bf16x8*)&lB[swz64(wn * 64 + j * 16 + lr, ks + q * 8)];
#pragma unroll
            for (int i = 0; i < 4; ++i)
#pragma unroll
                for (int j = 0; j < 4; ++j)
                    acc[i][j] = __builtin_amdgcn_mfma_f32_16x16x32_bf16(
                        af[i], bf[j], acc[i][j], 0, 0, 0);
        }
        __builtin_amdgcn_s_setprio(0);
    };

    // K = 512 -> 8 tiles, 2-step unrolled pipelined loop (out-counts: 8/tile)
    stage(lA0, lB0, 0);
#pragma unroll 1
    for (int kt2 = 0; kt2 < 4; ++kt2) {
        const int kt = kt2 * 2;
        stage(lA1, lB1, (long)(kt + 1) * 64);
        VMCNT(8);
        SCHED_FENCE();
        BARRIER();
        compute(lA0, lB0);
        SCHED_FENCE();
        BARRIER();
        if (kt2 < 3) {
            stage(lA0, lB0, (long)(kt + 2) * 64);
            VMCNT(8);
        } else {
            VMCNT(0);
        }
        SCHED_FENCE();
        BARRIER();
        compute(lA1, lB1);
        SCHED_FENCE();
        BARRIER();
    }

    // epilogue: C/D layout col=lane&15, row=(lane>>4)*4+reg
#pragma unroll
    for (int i = 0; i < 4; ++i) {
        const long r = arow0 + wm * 64 + i * 16 + q * 4;
#pragma unroll
        for (int j = 0; j < 4; ++j) {
            const long c = brow0 + wn * 64 + j * 16 + lr;
            const float bv2 = bias[c];
#pragma unroll
            for (int reg = 0; reg < 4; ++reg) {
                C[(r + reg) * N + c] = acc[i][j][reg] + bv2;
            }
        }
    }
}

// ---------------------------------------------------------------------------
extern "C" void kernel_launch(void* const* d_in, const int* in_sizes, int n_in,
                              void* d_out, int out_size, void* d_ws, size_t ws_size,
                              hipStream_t stream)
{
    (void)in_sizes; (void)n_in; (void)out_size;
    const float* x     = (const float*)d_in[0];  // [8,64,64,512] fp32
    const float* wqkv  = (const float*)d_in[1];  // [512,1536] fp32
    const float* wproj = (const float*)d_in[2];  // [512,512] fp32
    const float* bproj = (const float*)d_in[3];  // [512] fp32
    float* out = (float*)d_out;                  // [8,64,64,512] fp32

    // workspace: wT 1.5 MB + pT 0.5 MB + ao 32 MB (+ xb 32 MB when it fits)
    bf16_t* wT = (bf16_t*)d_ws;                  // [1536][512]
    bf16_t* pT = wT + (size_t)1536 * 512;        // [512][512]
    bf16_t* ao = pT + (size_t)512 * 512;         // [32768][512] proj layout

    // x pre-cast scratch: prefer workspace; fall back to d_out's first 32 MB
    // (fully overwritten by gemm2 afterwards, stream-ordered).
    const size_t base_elems = (size_t)1536 * 512 + (size_t)512 * 512
                            + (size_t)32768 * 512;
    const size_t xb_elems   = (size_t)32768 * 512;
    bf16_t* xb = (ws_size >= (base_elems + xb_elems) * sizeof(bf16_t))
               ? (ao + xb_elems)
               : (bf16_t*)d_out;

    transpose_cast_kernel<<<dim3(48, 16), 256, 0, stream>>>(wqkv, wT, 512, 1536);
    transpose_cast_kernel<<<dim3(16, 16), 256, 0, stream>>>(wproj, pT, 512, 512);
    cast_x_kernel<<<2048, 256, 0, stream>>>(x, xb, (long)32768 * 512 / 8);

    qkv_attn_kernel<<<2048, 256, 0, stream>>>(xb, wT, ao);

    gemm2_kernel<<<1024, 256, 0, stream>>>(
        ao, pT, bproj, out, 32768, 512, 512);
}